// Round 4
// baseline (413.168 us; speedup 1.0000x reference)
//
#include <hip/hip_runtime.h>
#include <cstdint>
#include <cstddef>

// Problem constants (reference: B=4, N=2048, DIM=256, heads=8, groups=2)
#define B_    4
#define NPT   2048
#define DIM_  256
#define QKVW  768   // 3*DIM

__device__ __forceinline__ float gelu_f(float x) {
  // exact gelu: x * 0.5 * (1 + erf(x/sqrt(2)))
  return 0.5f * x * (1.0f + erff(x * 0.70710678118654752440f));
}

// One DPP min-reduce step on a 64-bit key split into (hi,lo) halves (KNN).
template <int CTRL>
__device__ __forceinline__ void dppmin_step(int& lo, int& hi) {
  int olo = __builtin_amdgcn_update_dpp(lo, lo, CTRL, 0xf, 0xf, false);
  int ohi = __builtin_amdgcn_update_dpp(hi, hi, CTRL, 0xf, 0xf, false);
  unsigned long long o = ((unsigned long long)(unsigned)ohi << 32) | (unsigned)olo;
  unsigned long long c = ((unsigned long long)(unsigned)hi << 32) | (unsigned)lo;
  if (o < c) { lo = olo; hi = ohi; }
}

// DPP add step for float (invalid source lanes contribute 0 via old=0).
template <int CTRL>
__device__ __forceinline__ float dpp_addf(float x) {
  int s = __builtin_amdgcn_update_dpp(0, __float_as_int(x), CTRL, 0xf, 0xf, false);
  return x + __int_as_float(s);
}

// ---------------------------------------------------------------------------
// KNN v3: ONE WAVE per query (4 queries / 256-thread block). No barriers.
// Packed key = (dist_bits<<32)|idx; 2-level tournament per lane; wave min via
// 6-step DPP reduce ending in lane 63 -> readlane broadcast. (R3: 145->? µs,
// fell out of top-5.)
// ---------------------------------------------------------------------------
__global__ __launch_bounds__(256) void knn_kernel(const float* __restrict__ pos,
                                                  int* __restrict__ idx_out) {
  int wq = blockIdx.x * 4 + (threadIdx.x >> 6);  // query id 0..8191
  int lane = threadIdx.x & 63;
  int b = wq >> 11, n = wq & (NPT - 1);
  const float* pb = pos + (size_t)b * NPT * 3;
  float qx = pb[n * 3 + 0], qy = pb[n * 3 + 1], qz = pb[n * 3 + 2];

  unsigned long long keys[32];
  {
    // Match numpy rounding: no FMA contraction, left-to-right adds.
#pragma clang fp contract(off)
#pragma unroll
    for (int s = 0; s < 32; s++) {
      int j = lane + (s << 6);  // 64*32 = 2048 candidates, unique per lane
      float dx = qx - pb[j * 3 + 0];
      float dy = qy - pb[j * 3 + 1];
      float dz = qz - pb[j * 3 + 2];
      float d = dx * dx;
      d = d + dy * dy;
      d = d + dz * dz;
      keys[s] = ((unsigned long long)__float_as_uint(d) << 32) | (unsigned int)j;
    }
  }
  unsigned long long gk[4];
#pragma unroll
  for (int gi = 0; gi < 4; gi++) {
    unsigned long long m = keys[gi * 8];
#pragma unroll
    for (int s = 1; s < 8; s++) {
      unsigned long long c = keys[gi * 8 + s];
      m = (c < m) ? c : m;
    }
    gk[gi] = m;
  }
  unsigned long long lkey = gk[0];
#pragma unroll
  for (int gi = 1; gi < 4; gi++) lkey = (gk[gi] < lkey) ? gk[gi] : lkey;

  int* outp = idx_out + (size_t)wq * 32;
  for (int r = 0; r < 32; r++) {
    int lo = (int)(unsigned)(lkey & 0xffffffffULL);
    int hi = (int)(unsigned)(lkey >> 32);
    dppmin_step<0x111>(lo, hi);  // row_shr:1
    dppmin_step<0x112>(lo, hi);  // row_shr:2
    dppmin_step<0x114>(lo, hi);  // row_shr:4
    dppmin_step<0x118>(lo, hi);  // row_shr:8
    dppmin_step<0x142>(lo, hi);  // row_bcast:15
    dppmin_step<0x143>(lo, hi);  // row_bcast:31
    unsigned int glo = (unsigned int)__builtin_amdgcn_readlane(lo, 63);
    unsigned int ghi = (unsigned int)__builtin_amdgcn_readlane(hi, 63);
    unsigned long long g = ((unsigned long long)ghi << 32) | glo;
    if (lkey == g) {  // unique owner lane
      outp[r] = (int)glo;
#pragma unroll
      for (int gi = 0; gi < 4; gi++) {
        if (gk[gi] == g) {
          unsigned long long m = ~0ULL;
#pragma unroll
          for (int s = 0; s < 8; s++) {
            unsigned long long c = keys[gi * 8 + s];
            if (c == g) { c = ~0ULL; keys[gi * 8 + s] = c; }
            m = (c < m) ? c : m;
          }
          gk[gi] = m;
        }
      }
      lkey = gk[0];
#pragma unroll
      for (int gi = 1; gi < 4; gi++) lkey = (gk[gi] < lkey) ? gk[gi] : lkey;
    }
  }
}

// ---------------------------------------------------------------------------
// fp32 tiled GEMM, 64x64 tile, K-tile 16, 256 threads, 4x4 per thread.
// MODE 0: C = A@B                      (qkv)
// MODE 1: C = gelu(A@B + bias)        (proj)
// MODE 2: C = extra + (A*av)@B + bias (head; av indexed [batch*256+k], N==256)
// ---------------------------------------------------------------------------
template <int MODE>
__global__ __launch_bounds__(256) void gemm64(const float* __restrict__ A,
                                              const float* __restrict__ Bm,
                                              const float* __restrict__ bias,
                                              const float* __restrict__ extra,
                                              const float* __restrict__ av,
                                              float* __restrict__ C,
                                              int M, int N, int K) {
  __shared__ float As[16][65];  // [k][m], +1 pad
  __shared__ float Bs[16][64];  // [k][n]
  int tid = threadIdx.x;
  int tx = tid & 15, ty = tid >> 4;
  int tileN = blockIdx.x * 64, tileM = blockIdx.y * 64;
  int arow = tid >> 2;           // 0..63
  int acol4 = (tid & 3) * 4;     // 0,4,8,12
  int brow = tid >> 4;           // 0..15
  int bcol4 = (tid & 15) * 4;
  int batch = (tileM + arow) >> 11;  // rows of a tile share the batch (64|2048)
  float acc[4][4] = {};
  for (int k0 = 0; k0 < K; k0 += 16) {
    float4 a = *(const float4*)(A + (size_t)(tileM + arow) * K + k0 + acol4);
    if (MODE == 2) {
      const float* avb = av + batch * 256 + k0 + acol4;
      a.x *= avb[0]; a.y *= avb[1]; a.z *= avb[2]; a.w *= avb[3];
    }
    float4 bv = *(const float4*)(Bm + (size_t)(k0 + brow) * N + tileN + bcol4);
    As[acol4 + 0][arow] = a.x;
    As[acol4 + 1][arow] = a.y;
    As[acol4 + 2][arow] = a.z;
    As[acol4 + 3][arow] = a.w;
    *(float4*)&Bs[brow][bcol4] = bv;
    __syncthreads();
#pragma unroll
    for (int kk = 0; kk < 16; kk++) {
      float ar[4], br[4];
#pragma unroll
      for (int i = 0; i < 4; i++) ar[i] = As[kk][ty + 16 * i];
#pragma unroll
      for (int j = 0; j < 4; j++) br[j] = Bs[kk][tx + 16 * j];
#pragma unroll
      for (int i = 0; i < 4; i++)
#pragma unroll
        for (int j = 0; j < 4; j++) acc[i][j] += ar[i] * br[j];
    }
    __syncthreads();
  }
#pragma unroll
  for (int i = 0; i < 4; i++) {
    int row = tileM + ty + 16 * i;
#pragma unroll
    for (int j = 0; j < 4; j++) {
      int col = tileN + tx + 16 * j;
      float v = acc[i][j];
      if (MODE == 1) v = gelu_f(v + bias[col]);
      else if (MODE == 2) v = extra[(size_t)row * 256 + col] + (v + bias[col]);
      C[(size_t)row * N + col] = v;
    }
  }
}

// ---------------------------------------------------------------------------
// Attention v2: block=256 = one (b,n), thread t = global channel (g=t>>7,
// c=t&127, head row = t>>5). Key fold: logits[h][j] = sum_c(SCALE*q*k + rp)
// -> ONE 32-lane DPP reduce per neighbor covers q.k AND attn_rel. rp stays in
// 32 VGPRs (exactly what the output pass needs per-channel); k/v rows loaded
// coalesced (1 float/thread). LDS: idx+rel+logits only (~1.7 KB vs 18.4 KB).
// ---------------------------------------------------------------------------
__device__ __forceinline__ float head32_reduce(float u) {
  u = dpp_addf<0x111>(u);  // row_shr:1
  u = dpp_addf<0x112>(u);  // row_shr:2
  u = dpp_addf<0x114>(u);  // row_shr:4
  u = dpp_addf<0x118>(u);  // row_shr:8  -> lane15 of each row16 = row sum
  u = dpp_addf<0x142>(u);  // row_bcast:15 -> lane31/63 = 32-lane head sum
  return u;
}

template <int NK>
__device__ __forceinline__ void attn_phase1(const float* __restrict__ qkvb,
                                            const int* idx_s,
                                            const float (*rel_s)[3],
                                            float (*logits_s)[32],
                                            float* rp, float qS,
                                            float w0, float w1, float w2,
                                            float bb, int t) {
#pragma unroll
  for (int j = 0; j < NK; j++) {
    float x = rel_s[j][0] * w0 + rel_s[j][1] * w1 + rel_s[j][2] * w2 + bb;
    float r = gelu_f(x);
    rp[j] = r;
    float kv = qkvb[(size_t)idx_s[j] * QKVW + 256 + t];  // coalesced row read
    float u = fmaf(qS, kv, r);
    u = head32_reduce(u);
    if ((t & 31) == 31) logits_s[t >> 5][j] = u;  // writer is in readers' wave
  }
}

template <int NK>
__device__ __forceinline__ float attn_phase2(const float* __restrict__ qkvb,
                                             const int* idx_s,
                                             const float (*logits_s)[32],
                                             const float* rp, int t) {
  int h = t >> 5;
  float mx = -3.4e38f;
#pragma unroll
  for (int j = 0; j < NK; j++) mx = fmaxf(mx, logits_s[h][j]);
  float num = 0.f, den = 0.f;
#pragma unroll
  for (int j = 0; j < NK; j++) {
    float e = expf(logits_s[h][j] - mx);
    float v = qkvb[(size_t)idx_s[j] * QKVW + 512 + t];  // coalesced row read
    num += e * (v + rp[j]);
    den += e;
  }
  return num / den;
}

__global__ __launch_bounds__(256) void attn_kernel(
    const float* __restrict__ qkv, const float* __restrict__ pos,
    const int* __restrict__ knn,
    const float* __restrict__ Wp0, const float* __restrict__ bp0,
    const float* __restrict__ Wp1, const float* __restrict__ bp1,
    float* __restrict__ xcat) {
  const float SCALE = 0.17677669529663687f;  // 32^-0.5
  int bn = blockIdx.x;
  int b = bn >> 11, n = bn & (NPT - 1);
  int t = threadIdx.x;      // t = g*128 + c = qkv channel
  int g = t >> 7, c = t & 127;
  __shared__ int idx_s[32];
  __shared__ float rel_s[32][3];
  __shared__ float logits_s[8][32];
  const float* qkvb = qkv + (size_t)b * NPT * QKVW;
  if (t < 32) {
    int j = knn[(size_t)bn * 32 + t];
    idx_s[t] = j;
    const float* pn = pos + ((size_t)b * NPT + n) * 3;
    const float* pj = pos + ((size_t)b * NPT + j) * 3;
    rel_s[t][0] = pn[0] - pj[0];
    rel_s[t][1] = pn[1] - pj[1];
    rel_s[t][2] = pn[2] - pj[2];
  }
  float q = qkvb[(size_t)n * QKVW + t];
  const float* Wp = g ? Wp1 : Wp0;
  const float* bp = g ? bp1 : bp0;
  float w0 = Wp[c], w1 = Wp[128 + c], w2 = Wp[256 + c], bb = bp[c];
  float qS = q * SCALE;
  float rp[32];
  __syncthreads();
  if (g == 0)
    attn_phase1<16>(qkvb, idx_s, rel_s, logits_s, rp, qS, w0, w1, w2, bb, t);
  else
    attn_phase1<32>(qkvb, idx_s, rel_s, logits_s, rp, qS, w0, w1, w2, bb, t);
  __syncthreads();  // also orders logits_s for the compiler
  float o = (g == 0) ? attn_phase2<16>(qkvb, idx_s, logits_s, rp, t)
                     : attn_phase2<32>(qkvb, idx_s, logits_s, rp, t);
  xcat[((size_t)b * NPT + n) * DIM_ + t] = o;
}

// ---------------------------------------------------------------------------
// Column partial sums of feats_proj (mean over N later). grid (B,32), 64 rows each.
// ---------------------------------------------------------------------------
__global__ __launch_bounds__(256) void colsum_kernel(const float* __restrict__ fp,
                                                     float* __restrict__ part) {
  int b = blockIdx.x, ch = blockIdx.y, t = threadIdx.x;
  const float* base = fp + ((size_t)(b * NPT + ch * 64)) * DIM_ + t;
  float s = 0.f;
  for (int r = 0; r < 64; r++) s += base[(size_t)r * DIM_];
  part[((size_t)b * 32 + ch) * DIM_ + t] = s;
}

// ---------------------------------------------------------------------------
// Tiny MSF MLP: S=mean -> Z=gelu(S@Wfc1+b) -> av=Z@Wfc2+b -> pairwise softmax.
// ---------------------------------------------------------------------------
__global__ __launch_bounds__(256) void msf_small_kernel(
    const float* __restrict__ part, const float* __restrict__ Wfc1,
    const float* __restrict__ bfc1, const float* __restrict__ Wfc2,
    const float* __restrict__ bfc2, float* __restrict__ av_out) {
  int b = blockIdx.x, t = threadIdx.x;
  __shared__ float S[256], Z[128], A[256];
  float s = 0.f;
  for (int ch = 0; ch < 32; ch++) s += part[((size_t)b * 32 + ch) * DIM_ + t];
  S[t] = s * (1.0f / 2048.0f);
  __syncthreads();
  if (t < 128) {
    float z = bfc1[t];
    for (int i = 0; i < 256; i++) z += S[i] * Wfc1[i * 128 + t];
    Z[t] = gelu_f(z);
  }
  __syncthreads();
  float a = bfc2[t];
  for (int j = 0; j < 128; j++) a += Z[j] * Wfc2[j * 256 + t];
  A[t] = a;
  __syncthreads();
  float pA = A[t ^ 128];  // softmax over the 2 groups, per channel
  float m = fmaxf(a, pA);
  float e = expf(a - m);
  av_out[(size_t)b * 256 + t] = e / (e + expf(pA - m));
}

// ---------------------------------------------------------------------------
extern "C" void kernel_launch(void* const* d_in, const int* in_sizes, int n_in,
                              void* d_out, int out_size, void* d_ws, size_t ws_size,
                              hipStream_t stream) {
  const float* x     = (const float*)d_in[0];
  const float* pos   = (const float*)d_in[1];
  const float* Wqkv  = (const float*)d_in[2];
  const float* Wp0   = (const float*)d_in[3];
  const float* bp0   = (const float*)d_in[4];
  const float* Wp1   = (const float*)d_in[5];
  const float* bp1   = (const float*)d_in[6];
  const float* Wproj = (const float*)d_in[7];
  const float* bproj = (const float*)d_in[8];
  const float* Wfc1  = (const float*)d_in[9];
  const float* bfc1  = (const float*)d_in[10];
  const float* Wfc2  = (const float*)d_in[11];
  const float* bfc2  = (const float*)d_in[12];
  const float* Whead = (const float*)d_in[13];
  const float* bhead = (const float*)d_in[14];
  float* out = (float*)d_out;

  char* ws = (char*)d_ws;
  size_t off = 0;
  int* idx = (int*)(ws + off);          off += (size_t)B_ * NPT * 32 * 4;      // 1 MiB
  float* qkv = (float*)(ws + off);      off += (size_t)B_ * NPT * QKVW * 4;    // 25.2 MB
  float* fp = qkv;  // reuse: qkv dead after attention
  float* xcat = (float*)(ws + off);     off += (size_t)B_ * NPT * DIM_ * 4;    // 8.4 MB
  float* part = (float*)(ws + off);     off += (size_t)B_ * 32 * DIM_ * 4;     // 128 KiB
  float* av = (float*)(ws + off);       off += (size_t)B_ * DIM_ * 4;          // 4 KiB

  const int M = B_ * NPT;  // 8192

  knn_kernel<<<M / 4, 256, 0, stream>>>(pos, idx);
  gemm64<0><<<dim3(QKVW / 64, M / 64), 256, 0, stream>>>(
      x, Wqkv, nullptr, nullptr, nullptr, qkv, M, QKVW, DIM_);
  attn_kernel<<<M, 256, 0, stream>>>(qkv, pos, idx, Wp0, bp0, Wp1, bp1, xcat);
  gemm64<1><<<dim3(DIM_ / 64, M / 64), 256, 0, stream>>>(
      xcat, Wproj, bproj, nullptr, nullptr, fp, M, DIM_, DIM_);
  colsum_kernel<<<dim3(B_, 32), 256, 0, stream>>>(fp, part);
  msf_small_kernel<<<B_, 256, 0, stream>>>(part, Wfc1, bfc1, Wfc2, bfc2, av);
  gemm64<2><<<dim3(DIM_ / 64, M / 64), 256, 0, stream>>>(
      xcat, Whead, bhead, fp, av, out, M, DIM_, DIM_);
}

// Round 5
// 349.148 us; speedup vs baseline: 1.1834x; 1.1834x over previous
//
#include <hip/hip_runtime.h>
#include <cstdint>
#include <cstddef>

// Problem constants (reference: B=4, N=2048, DIM=256, heads=8, groups=2)
#define B_    4
#define NPT   2048
#define DIM_  256
#define QKVW  768   // 3*DIM

__device__ __forceinline__ float gelu_f(float x) {
  // exact gelu: x * 0.5 * (1 + erf(x/sqrt(2)))
  return 0.5f * x * (1.0f + erff(x * 0.70710678118654752440f));
}

// Fast gelu: Abramowitz-Stegun 7.1.26 erf (max abs err 1.5e-7 -- invisible at
// our 3.7e-2 threshold), ~15 VALU incl. v_rcp/v_exp, no libm call.
__device__ __forceinline__ float gelu_fast(float x) {
  const float is2 = 0.70710678118654752440f;
  float z = x * is2;
  float az = __builtin_fabsf(z);
  float t = __builtin_amdgcn_rcpf(fmaf(0.3275911f, az, 1.0f));
  float p = fmaf(1.061405429f, t, -1.453152027f);
  p = fmaf(p, t, 1.421413741f);
  p = fmaf(p, t, -0.284496736f);
  p = fmaf(p, t, 0.254829592f);
  p = p * t;
  float e = __expf(-az * az);
  float er = fmaf(-p, e, 1.0f);           // erf(|z|)
  er = __builtin_copysignf(er, x);        // erf(z)
  return 0.5f * x * (1.0f + er);
}

// One DPP min-reduce step on a 64-bit key split into (hi,lo) halves (KNN).
template <int CTRL>
__device__ __forceinline__ void dppmin_step(int& lo, int& hi) {
  int olo = __builtin_amdgcn_update_dpp(lo, lo, CTRL, 0xf, 0xf, false);
  int ohi = __builtin_amdgcn_update_dpp(hi, hi, CTRL, 0xf, 0xf, false);
  unsigned long long o = ((unsigned long long)(unsigned)ohi << 32) | (unsigned)olo;
  unsigned long long c = ((unsigned long long)(unsigned)hi << 32) | (unsigned)lo;
  if (o < c) { lo = olo; hi = ohi; }
}

// DPP add step for float (invalid source lanes contribute 0 via old=0).
template <int CTRL>
__device__ __forceinline__ float dpp_addf(float x) {
  int s = __builtin_amdgcn_update_dpp(0, __float_as_int(x), CTRL, 0xf, 0xf, false);
  return x + __int_as_float(s);
}

// ---------------------------------------------------------------------------
// KNN v3: ONE WAVE per query (4 queries / 256-thread block). No barriers.
// Packed key = (dist_bits<<32)|idx; 2-level tournament per lane; wave min via
// 6-step DPP reduce ending in lane 63 -> readlane broadcast.
// ---------------------------------------------------------------------------
__global__ __launch_bounds__(256) void knn_kernel(const float* __restrict__ pos,
                                                  int* __restrict__ idx_out) {
  int wq = blockIdx.x * 4 + (threadIdx.x >> 6);  // query id 0..8191
  int lane = threadIdx.x & 63;
  int b = wq >> 11, n = wq & (NPT - 1);
  const float* pb = pos + (size_t)b * NPT * 3;
  float qx = pb[n * 3 + 0], qy = pb[n * 3 + 1], qz = pb[n * 3 + 2];

  unsigned long long keys[32];
  {
    // Match numpy rounding: no FMA contraction, left-to-right adds.
#pragma clang fp contract(off)
#pragma unroll
    for (int s = 0; s < 32; s++) {
      int j = lane + (s << 6);  // 64*32 = 2048 candidates, unique per lane
      float dx = qx - pb[j * 3 + 0];
      float dy = qy - pb[j * 3 + 1];
      float dz = qz - pb[j * 3 + 2];
      float d = dx * dx;
      d = d + dy * dy;
      d = d + dz * dz;
      keys[s] = ((unsigned long long)__float_as_uint(d) << 32) | (unsigned int)j;
    }
  }
  unsigned long long gk[4];
#pragma unroll
  for (int gi = 0; gi < 4; gi++) {
    unsigned long long m = keys[gi * 8];
#pragma unroll
    for (int s = 1; s < 8; s++) {
      unsigned long long c = keys[gi * 8 + s];
      m = (c < m) ? c : m;
    }
    gk[gi] = m;
  }
  unsigned long long lkey = gk[0];
#pragma unroll
  for (int gi = 1; gi < 4; gi++) lkey = (gk[gi] < lkey) ? gk[gi] : lkey;

  int* outp = idx_out + (size_t)wq * 32;
  for (int r = 0; r < 32; r++) {
    int lo = (int)(unsigned)(lkey & 0xffffffffULL);
    int hi = (int)(unsigned)(lkey >> 32);
    dppmin_step<0x111>(lo, hi);  // row_shr:1
    dppmin_step<0x112>(lo, hi);  // row_shr:2
    dppmin_step<0x114>(lo, hi);  // row_shr:4
    dppmin_step<0x118>(lo, hi);  // row_shr:8
    dppmin_step<0x142>(lo, hi);  // row_bcast:15
    dppmin_step<0x143>(lo, hi);  // row_bcast:31
    unsigned int glo = (unsigned int)__builtin_amdgcn_readlane(lo, 63);
    unsigned int ghi = (unsigned int)__builtin_amdgcn_readlane(hi, 63);
    unsigned long long g = ((unsigned long long)ghi << 32) | glo;
    if (lkey == g) {  // unique owner lane
      outp[r] = (int)glo;
#pragma unroll
      for (int gi = 0; gi < 4; gi++) {
        if (gk[gi] == g) {
          unsigned long long m = ~0ULL;
#pragma unroll
          for (int s = 0; s < 8; s++) {
            unsigned long long c = keys[gi * 8 + s];
            if (c == g) { c = ~0ULL; keys[gi * 8 + s] = c; }
            m = (c < m) ? c : m;
          }
          gk[gi] = m;
        }
      }
      lkey = gk[0];
#pragma unroll
      for (int gi = 1; gi < 4; gi++) lkey = (gk[gi] < lkey) ? gk[gi] : lkey;
    }
  }
}

// ---------------------------------------------------------------------------
// fp32 tiled GEMM, 64x64 tile, K-tile 16, 256 threads, 4x4 per thread.
// MODE 0: C = A@B                      (qkv)
// MODE 1: C = gelu(A@B + bias)        (proj)
// MODE 2: C = extra + (A*av)@B + bias (head; av indexed [batch*256+k], N==256)
// ---------------------------------------------------------------------------
template <int MODE>
__global__ __launch_bounds__(256) void gemm64(const float* __restrict__ A,
                                              const float* __restrict__ Bm,
                                              const float* __restrict__ bias,
                                              const float* __restrict__ extra,
                                              const float* __restrict__ av,
                                              float* __restrict__ C,
                                              int M, int N, int K) {
  __shared__ float As[16][65];  // [k][m], +1 pad
  __shared__ float Bs[16][64];  // [k][n]
  int tid = threadIdx.x;
  int tx = tid & 15, ty = tid >> 4;
  int tileN = blockIdx.x * 64, tileM = blockIdx.y * 64;
  int arow = tid >> 2;           // 0..63
  int acol4 = (tid & 3) * 4;     // 0,4,8,12
  int brow = tid >> 4;           // 0..15
  int bcol4 = (tid & 15) * 4;
  int batch = (tileM + arow) >> 11;  // rows of a tile share the batch (64|2048)
  float acc[4][4] = {};
  for (int k0 = 0; k0 < K; k0 += 16) {
    float4 a = *(const float4*)(A + (size_t)(tileM + arow) * K + k0 + acol4);
    if (MODE == 2) {
      const float* avb = av + batch * 256 + k0 + acol4;
      a.x *= avb[0]; a.y *= avb[1]; a.z *= avb[2]; a.w *= avb[3];
    }
    float4 bv = *(const float4*)(Bm + (size_t)(k0 + brow) * N + tileN + bcol4);
    As[acol4 + 0][arow] = a.x;
    As[acol4 + 1][arow] = a.y;
    As[acol4 + 2][arow] = a.z;
    As[acol4 + 3][arow] = a.w;
    *(float4*)&Bs[brow][bcol4] = bv;
    __syncthreads();
#pragma unroll
    for (int kk = 0; kk < 16; kk++) {
      float ar[4], br[4];
#pragma unroll
      for (int i = 0; i < 4; i++) ar[i] = As[kk][ty + 16 * i];
#pragma unroll
      for (int j = 0; j < 4; j++) br[j] = Bs[kk][tx + 16 * j];
#pragma unroll
      for (int i = 0; i < 4; i++)
#pragma unroll
        for (int j = 0; j < 4; j++) acc[i][j] += ar[i] * br[j];
    }
    __syncthreads();
  }
#pragma unroll
  for (int i = 0; i < 4; i++) {
    int row = tileM + ty + 16 * i;
#pragma unroll
    for (int j = 0; j < 4; j++) {
      int col = tileN + tx + 16 * j;
      float v = acc[i][j];
      if (MODE == 1) v = gelu_f(v + bias[col]);
      else if (MODE == 2) v = extra[(size_t)row * 256 + col] + (v + bias[col]);
      C[(size_t)row * N + col] = v;
    }
  }
}

// ---------------------------------------------------------------------------
// Attention v3: block=256 = one (b,n), thread t = qkv channel. Fold:
// logits[h][j] = sum_c(SCALE*q*k + rp) -> one 32-lane DPP reduce per neighbor.
// Fixes vs R4 (142 µs, VALUBusy 54%): (1) gather bases via readfirstlane ->
// SGPR addressing (no per-j 64-bit VGPR addr math); (2) NO second barrier --
// logits_s[h] writer (lane h*32+31) and readers are the SAME wave, so
// s_waitcnt lgkmcnt(0) + compiler fence suffices and the 16-neighbor waves
// never wait on the 32-neighbor waves; (3) gelu_fast + __expf.
// ---------------------------------------------------------------------------
__device__ __forceinline__ float head32_reduce(float u) {
  u = dpp_addf<0x111>(u);  // row_shr:1
  u = dpp_addf<0x112>(u);  // row_shr:2
  u = dpp_addf<0x114>(u);  // row_shr:4
  u = dpp_addf<0x118>(u);  // row_shr:8  -> lane15 of each row16 = row sum
  u = dpp_addf<0x142>(u);  // row_bcast:15 -> lane31/63 = 32-lane head sum
  return u;
}

template <int NK>
__device__ __forceinline__ float attn_group(const float* __restrict__ qkvb,
                                            const int* idx_s,
                                            const float (*rel_s)[3],
                                            float (*logits_s)[32],
                                            float qS, float w0, float w1,
                                            float w2, float bb, int t) {
  float rp[NK];
  bool writer = ((t & 31) == 31);
  int h = t >> 5;
  // pass 1: rp + folded logits
#pragma unroll
  for (int j = 0; j < NK; j++) {
    int jj = __builtin_amdgcn_readfirstlane(idx_s[j]);  // wave-uniform -> SGPR
    const float* kr = qkvb + (size_t)jj * QKVW + 256;   // scalar base
    float kv = kr[t];                                   // coalesced row read
    float x = fmaf(rel_s[j][0], w0,
              fmaf(rel_s[j][1], w1, fmaf(rel_s[j][2], w2, bb)));
    float r = gelu_fast(x);
    rp[j] = r;
    float u = head32_reduce(fmaf(qS, kv, r));
    if (writer) logits_s[h][j] = u;
  }
  // intra-wave LDS write->read: drain lgkm, fence compiler reordering.
  __builtin_amdgcn_wave_barrier();
  asm volatile("s_waitcnt lgkmcnt(0)" ::: "memory");
  // pass 2: softmax + output accumulation (per-thread registers)
  float mx = -3.4e38f;
#pragma unroll
  for (int j = 0; j < NK; j++) mx = fmaxf(mx, logits_s[h][j]);
  float num = 0.f, den = 0.f;
#pragma unroll
  for (int j = 0; j < NK; j++) {
    float e = __expf(logits_s[h][j] - mx);
    int jj = __builtin_amdgcn_readfirstlane(idx_s[j]);
    const float* vr = qkvb + (size_t)jj * QKVW + 512;
    float v = vr[t];                                    // coalesced row read
    num = fmaf(e, v + rp[j], num);
    den += e;
  }
  return num * __builtin_amdgcn_rcpf(den);
}

__global__ __launch_bounds__(256) void attn_kernel(
    const float* __restrict__ qkv, const float* __restrict__ pos,
    const int* __restrict__ knn,
    const float* __restrict__ Wp0, const float* __restrict__ bp0,
    const float* __restrict__ Wp1, const float* __restrict__ bp1,
    float* __restrict__ xcat) {
  const float SCALE = 0.17677669529663687f;  // 32^-0.5
  int bn = blockIdx.x;
  int b = bn >> 11, n = bn & (NPT - 1);
  int t = threadIdx.x;      // t = g*128 + c = qkv channel
  int g = t >> 7, c = t & 127;
  __shared__ int idx_s[32];
  __shared__ float rel_s[32][3];
  __shared__ float logits_s[8][32];
  const float* qkvb = qkv + (size_t)b * NPT * QKVW;
  if (t < 32) {
    int j = knn[(size_t)bn * 32 + t];
    idx_s[t] = j;
    const float* pn = pos + ((size_t)b * NPT + n) * 3;
    const float* pj = pos + ((size_t)b * NPT + j) * 3;
    rel_s[t][0] = pn[0] - pj[0];
    rel_s[t][1] = pn[1] - pj[1];
    rel_s[t][2] = pn[2] - pj[2];
  }
  float q = qkvb[(size_t)n * QKVW + t];
  const float* Wp = g ? Wp1 : Wp0;
  const float* bp = g ? bp1 : bp0;
  float w0 = Wp[c], w1 = Wp[128 + c], w2 = Wp[256 + c], bb = bp[c];
  float qS = q * SCALE;
  __syncthreads();  // the ONLY block barrier: idx_s/rel_s staged by wave 0
  float o = (g == 0)
      ? attn_group<16>(qkvb, idx_s, rel_s, logits_s, qS, w0, w1, w2, bb, t)
      : attn_group<32>(qkvb, idx_s, rel_s, logits_s, qS, w0, w1, w2, bb, t);
  xcat[((size_t)b * NPT + n) * DIM_ + t] = o;
}

// ---------------------------------------------------------------------------
// Column partial sums of feats_proj (mean over N later). grid (B,32), 64 rows each.
// ---------------------------------------------------------------------------
__global__ __launch_bounds__(256) void colsum_kernel(const float* __restrict__ fp,
                                                     float* __restrict__ part) {
  int b = blockIdx.x, ch = blockIdx.y, t = threadIdx.x;
  const float* base = fp + ((size_t)(b * NPT + ch * 64)) * DIM_ + t;
  float s = 0.f;
  for (int r = 0; r < 64; r++) s += base[(size_t)r * DIM_];
  part[((size_t)b * 32 + ch) * DIM_ + t] = s;
}

// ---------------------------------------------------------------------------
// Tiny MSF MLP: S=mean -> Z=gelu(S@Wfc1+b) -> av=Z@Wfc2+b -> pairwise softmax.
// ---------------------------------------------------------------------------
__global__ __launch_bounds__(256) void msf_small_kernel(
    const float* __restrict__ part, const float* __restrict__ Wfc1,
    const float* __restrict__ bfc1, const float* __restrict__ Wfc2,
    const float* __restrict__ bfc2, float* __restrict__ av_out) {
  int b = blockIdx.x, t = threadIdx.x;
  __shared__ float S[256], Z[128], A[256];
  float s = 0.f;
  for (int ch = 0; ch < 32; ch++) s += part[((size_t)b * 32 + ch) * DIM_ + t];
  S[t] = s * (1.0f / 2048.0f);
  __syncthreads();
  if (t < 128) {
    float z = bfc1[t];
    for (int i = 0; i < 256; i++) z += S[i] * Wfc1[i * 128 + t];
    Z[t] = gelu_f(z);
  }
  __syncthreads();
  float a = bfc2[t];
  for (int j = 0; j < 128; j++) a += Z[j] * Wfc2[j * 256 + t];
  A[t] = a;
  __syncthreads();
  float pA = A[t ^ 128];  // softmax over the 2 groups, per channel
  float m = fmaxf(a, pA);
  float e = expf(a - m);
  av_out[(size_t)b * 256 + t] = e / (e + expf(pA - m));
}

// ---------------------------------------------------------------------------
extern "C" void kernel_launch(void* const* d_in, const int* in_sizes, int n_in,
                              void* d_out, int out_size, void* d_ws, size_t ws_size,
                              hipStream_t stream) {
  const float* x     = (const float*)d_in[0];
  const float* pos   = (const float*)d_in[1];
  const float* Wqkv  = (const float*)d_in[2];
  const float* Wp0   = (const float*)d_in[3];
  const float* bp0   = (const float*)d_in[4];
  const float* Wp1   = (const float*)d_in[5];
  const float* bp1   = (const float*)d_in[6];
  const float* Wproj = (const float*)d_in[7];
  const float* bproj = (const float*)d_in[8];
  const float* Wfc1  = (const float*)d_in[9];
  const float* bfc1  = (const float*)d_in[10];
  const float* Wfc2  = (const float*)d_in[11];
  const float* bfc2  = (const float*)d_in[12];
  const float* Whead = (const float*)d_in[13];
  const float* bhead = (const float*)d_in[14];
  float* out = (float*)d_out;

  char* ws = (char*)d_ws;
  size_t off = 0;
  int* idx = (int*)(ws + off);          off += (size_t)B_ * NPT * 32 * 4;      // 1 MiB
  float* qkv = (float*)(ws + off);      off += (size_t)B_ * NPT * QKVW * 4;    // 25.2 MB
  float* fp = qkv;  // reuse: qkv dead after attention
  float* xcat = (float*)(ws + off);     off += (size_t)B_ * NPT * DIM_ * 4;    // 8.4 MB
  float* part = (float*)(ws + off);     off += (size_t)B_ * 32 * DIM_ * 4;     // 128 KiB
  float* av = (float*)(ws + off);       off += (size_t)B_ * DIM_ * 4;          // 4 KiB

  const int M = B_ * NPT;  // 8192

  knn_kernel<<<M / 4, 256, 0, stream>>>(pos, idx);
  gemm64<0><<<dim3(QKVW / 64, M / 64), 256, 0, stream>>>(
      x, Wqkv, nullptr, nullptr, nullptr, qkv, M, QKVW, DIM_);
  attn_kernel<<<M, 256, 0, stream>>>(qkv, pos, idx, Wp0, bp0, Wp1, bp1, xcat);
  gemm64<1><<<dim3(DIM_ / 64, M / 64), 256, 0, stream>>>(
      xcat, Wproj, bproj, nullptr, nullptr, fp, M, DIM_, DIM_);
  colsum_kernel<<<dim3(B_, 32), 256, 0, stream>>>(fp, part);
  msf_small_kernel<<<B_, 256, 0, stream>>>(part, Wfc1, bfc1, Wfc2, bfc2, av);
  gemm64<2><<<dim3(DIM_ / 64, M / 64), 256, 0, stream>>>(
      xcat, Whead, bhead, fp, av, out, M, DIM_, DIM_);
}

// Round 6
// 313.389 us; speedup vs baseline: 1.3184x; 1.1141x over previous
//
#include <hip/hip_runtime.h>
#include <cstdint>
#include <cstddef>

// Problem constants (reference: B=4, N=2048, DIM=256, heads=8, groups=2)
#define B_    4
#define NPT   2048
#define DIM_  256
#define QKVW  768   // 3*DIM

typedef unsigned short ushort_t;
typedef short bf16x8 __attribute__((ext_vector_type(8)));
typedef float f32x4 __attribute__((ext_vector_type(4)));

__device__ __forceinline__ float gelu_f(float x) {
  return 0.5f * x * (1.0f + erff(x * 0.70710678118654752440f));
}

// Fast gelu: A&S 7.1.26 erf (max abs err 1.5e-7), no libm call.
__device__ __forceinline__ float gelu_fast(float x) {
  const float is2 = 0.70710678118654752440f;
  float z = x * is2;
  float az = __builtin_fabsf(z);
  float t = __builtin_amdgcn_rcpf(fmaf(0.3275911f, az, 1.0f));
  float p = fmaf(1.061405429f, t, -1.453152027f);
  p = fmaf(p, t, 1.421413741f);
  p = fmaf(p, t, -0.284496736f);
  p = fmaf(p, t, 0.254829592f);
  p = p * t;
  float e = __expf(-az * az);
  float er = fmaf(-p, e, 1.0f);
  er = __builtin_copysignf(er, x);
  return 0.5f * x * (1.0f + er);
}

// fp32 -> bf16 round-to-nearest-even (matches numpy/jax casting)
__device__ __forceinline__ ushort_t f2bf(float f) {
  unsigned u = __float_as_uint(f);
  unsigned r = (u + 0x7fffu + ((u >> 16) & 1u)) >> 16;
  return (ushort_t)r;
}
__device__ __forceinline__ float bf2f(ushort_t h) {
  return __uint_as_float(((unsigned)h) << 16);
}

// async global->LDS, 16 B per lane; LDS dest = uniform base + lane*16.
__device__ __forceinline__ void gl_lds16(const void* g, void* l) {
  __builtin_amdgcn_global_load_lds(
      (const __attribute__((address_space(1))) unsigned int*)g,
      (__attribute__((address_space(3))) unsigned int*)l, 16, 0, 0);
}

// One DPP min-reduce step on a 64-bit key split into (hi,lo) halves (KNN).
template <int CTRL>
__device__ __forceinline__ void dppmin_step(int& lo, int& hi) {
  int olo = __builtin_amdgcn_update_dpp(lo, lo, CTRL, 0xf, 0xf, false);
  int ohi = __builtin_amdgcn_update_dpp(hi, hi, CTRL, 0xf, 0xf, false);
  unsigned long long o = ((unsigned long long)(unsigned)ohi << 32) | (unsigned)olo;
  unsigned long long c = ((unsigned long long)(unsigned)hi << 32) | (unsigned)lo;
  if (o < c) { lo = olo; hi = ohi; }
}

// DPP add step for float (invalid source lanes contribute 0 via old=0).
template <int CTRL>
__device__ __forceinline__ float dpp_addf(float x) {
  int s = __builtin_amdgcn_update_dpp(0, __float_as_int(x), CTRL, 0xf, 0xf, false);
  return x + __int_as_float(s);
}

// ---------------------------------------------------------------------------
// Convert kernel: xbf = bf16(x); WqkvT/WprojT/WheadT = bf16(W^T) (k-contig
// rows = MFMA B-operand format). One flat launch over all 2.42M elements.
// ---------------------------------------------------------------------------
#define XLEN  2097152   // 8192*256
#define QLEN  196608    // 768*256
#define PLEN  65536     // 256*256
__global__ __launch_bounds__(256) void convert_kernel(
    const float* __restrict__ x, const float* __restrict__ Wqkv,
    const float* __restrict__ Wproj, const float* __restrict__ Whead,
    ushort_t* __restrict__ xbf, ushort_t* __restrict__ WqkvT,
    ushort_t* __restrict__ WprojT, ushort_t* __restrict__ WheadT) {
  int i = blockIdx.x * 256 + threadIdx.x;
  if (i < XLEN) {
    xbf[i] = f2bf(x[i]);
  } else if (i < XLEN + QLEN) {
    int e = i - XLEN; int n = e >> 8, k = e & 255;
    WqkvT[e] = f2bf(Wqkv[k * 768 + n]);
  } else if (i < XLEN + QLEN + PLEN) {
    int e = i - XLEN - QLEN; int n = e >> 8, k = e & 255;
    WprojT[e] = f2bf(Wproj[k * 256 + n]);
  } else {
    int e = i - XLEN - QLEN - PLEN; int n = e >> 8, k = e & 255;
    WheadT[e] = f2bf(Whead[k * 256 + n]);
  }
}

// ---------------------------------------------------------------------------
// KNN: ONE WAVE per query. Packed key=(dist_bits<<32)|idx, DPP wave-min.
// ---------------------------------------------------------------------------
__global__ __launch_bounds__(256) void knn_kernel(const float* __restrict__ pos,
                                                  int* __restrict__ idx_out) {
  int wq = blockIdx.x * 4 + (threadIdx.x >> 6);
  int lane = threadIdx.x & 63;
  int b = wq >> 11, n = wq & (NPT - 1);
  const float* pb = pos + (size_t)b * NPT * 3;
  float qx = pb[n * 3 + 0], qy = pb[n * 3 + 1], qz = pb[n * 3 + 2];

  unsigned long long keys[32];
  {
#pragma clang fp contract(off)
#pragma unroll
    for (int s = 0; s < 32; s++) {
      int j = lane + (s << 6);
      float dx = qx - pb[j * 3 + 0];
      float dy = qy - pb[j * 3 + 1];
      float dz = qz - pb[j * 3 + 2];
      float d = dx * dx;
      d = d + dy * dy;
      d = d + dz * dz;
      keys[s] = ((unsigned long long)__float_as_uint(d) << 32) | (unsigned int)j;
    }
  }
  unsigned long long gk[4];
#pragma unroll
  for (int gi = 0; gi < 4; gi++) {
    unsigned long long m = keys[gi * 8];
#pragma unroll
    for (int s = 1; s < 8; s++) {
      unsigned long long c = keys[gi * 8 + s];
      m = (c < m) ? c : m;
    }
    gk[gi] = m;
  }
  unsigned long long lkey = gk[0];
#pragma unroll
  for (int gi = 1; gi < 4; gi++) lkey = (gk[gi] < lkey) ? gk[gi] : lkey;

  int* outp = idx_out + (size_t)wq * 32;
  for (int r = 0; r < 32; r++) {
    int lo = (int)(unsigned)(lkey & 0xffffffffULL);
    int hi = (int)(unsigned)(lkey >> 32);
    dppmin_step<0x111>(lo, hi);
    dppmin_step<0x112>(lo, hi);
    dppmin_step<0x114>(lo, hi);
    dppmin_step<0x118>(lo, hi);
    dppmin_step<0x142>(lo, hi);
    dppmin_step<0x143>(lo, hi);
    unsigned int glo = (unsigned int)__builtin_amdgcn_readlane(lo, 63);
    unsigned int ghi = (unsigned int)__builtin_amdgcn_readlane(hi, 63);
    unsigned long long g = ((unsigned long long)ghi << 32) | glo;
    if (lkey == g) {
      outp[r] = (int)glo;
#pragma unroll
      for (int gi = 0; gi < 4; gi++) {
        if (gk[gi] == g) {
          unsigned long long m = ~0ULL;
#pragma unroll
          for (int s = 0; s < 8; s++) {
            unsigned long long c = keys[gi * 8 + s];
            if (c == g) { c = ~0ULL; keys[gi * 8 + s] = c; }
            m = (c < m) ? c : m;
          }
          gk[gi] = m;
        }
      }
      lkey = gk[0];
#pragma unroll
      for (int gi = 1; gi < 4; gi++) lkey = (gk[gi] < lkey) ? gk[gi] : lkey;
    }
  }
}

// ---------------------------------------------------------------------------
// bf16 MFMA GEMM: C[M][N] = A[M][256] @ B[256][N], A bf16 row-major,
// BT bf16 [N][256] (k-contig per row). 128x128 tile, 4 waves, each 64x64 via
// 4x4 grid of 16x16x32 MFMAs, fp32 acc. LDS layout k-major in 16B units
// (unit u = kc*128 + m): staging = global_load_lds lane-contiguous, frag
// reads = quarter-wave-contiguous ds_read_b128 (conflict-free).
// MODE 0: C = acc                   (qkv, N=768)
// MODE 1: C = gelu(acc + bias)      (feats_proj)
// MODE 2: C = extra + acc + bias    (head; BT = per-batch av-scaled WheadT)
// ---------------------------------------------------------------------------
template <int MODE>
__global__ __launch_bounds__(256) void gemm_mfma(
    const ushort_t* __restrict__ A, const ushort_t* __restrict__ BT,
    const float* __restrict__ bias, const float* __restrict__ extra,
    float* __restrict__ C, int N) {
  constexpr int K = 256;
  __shared__ ushort_t As[4096];  // 8 KB
  __shared__ ushort_t Bs[4096];  // 8 KB
  int tid = threadIdx.x;
  int wave = tid >> 6, lane = tid & 63;
  int quad = lane >> 4, r16 = lane & 15;
  int m0 = blockIdx.y * 128, n0 = blockIdx.x * 128;
  int wm = (wave >> 1) * 64, wn = (wave & 1) * 64;
  f32x4 acc[4][4] = {};
  const ushort_t* Ab = A + (size_t)m0 * K;
  const ushort_t* Bb = (MODE == 2)
      ? BT + ((size_t)(m0 >> 11) * N + n0) * K   // per-batch scaled Whead^T
      : BT + (size_t)n0 * K;
  for (int k0 = 0; k0 < K; k0 += 32) {
    __syncthreads();  // previous iter's ds_reads done before overwrite
    // wave w stages k-chunk kc=w for all 128 rows of A and B (2 issues each)
#pragma unroll
    for (int s = 0; s < 2; s++) {
      gl_lds16(Ab + (size_t)(s * 64 + lane) * K + k0 + wave * 8,
               &As[(wave * 128 + s * 64) * 8]);
      gl_lds16(Bb + (size_t)(s * 64 + lane) * K + k0 + wave * 8,
               &Bs[(wave * 128 + s * 64) * 8]);
    }
    asm volatile("s_waitcnt vmcnt(0)" ::: "memory");
    __syncthreads();
    bf16x8 af[4], bfr[4];
#pragma unroll
    for (int i = 0; i < 4; i++) {
      af[i]  = *(const bf16x8*)&As[(quad * 128 + wm + i * 16 + r16) * 8];
      bfr[i] = *(const bf16x8*)&Bs[(quad * 128 + wn + i * 16 + r16) * 8];
    }
#pragma unroll
    for (int i = 0; i < 4; i++)
#pragma unroll
      for (int j = 0; j < 4; j++)
        acc[i][j] = __builtin_amdgcn_mfma_f32_16x16x32_bf16(
            af[i], bfr[j], acc[i][j], 0, 0, 0);
  }
  // epilogue: C/D layout col=lane&15, row=quad*4+reg (m89-verified)
#pragma unroll
  for (int i = 0; i < 4; i++) {
#pragma unroll
    for (int j = 0; j < 4; j++) {
      int col = n0 + wn + j * 16 + r16;
#pragma unroll
      for (int r = 0; r < 4; r++) {
        int row = m0 + wm + i * 16 + quad * 4 + r;
        float v = acc[i][j][r];
        if (MODE == 1) v = gelu_fast(v + bias[col]);
        else if (MODE == 2) v = extra[(size_t)row * 256 + col] + v + bias[col];
        C[(size_t)row * N + col] = v;
      }
    }
  }
}

// ---------------------------------------------------------------------------
// Attention: block=256 = one (b,n), thread t = qkv channel. Folded logits via
// 32-lane DPP reduce; SGPR-base gathers; single block barrier. Output written
// as bf16 (consumed only as MFMA A-operands by gemm1/gemm2).
// ---------------------------------------------------------------------------
__device__ __forceinline__ float head32_reduce(float u) {
  u = dpp_addf<0x111>(u);
  u = dpp_addf<0x112>(u);
  u = dpp_addf<0x114>(u);
  u = dpp_addf<0x118>(u);
  u = dpp_addf<0x142>(u);
  return u;
}

template <int NK>
__device__ __forceinline__ float attn_group(const float* __restrict__ qkvb,
                                            const int* idx_s,
                                            const float (*rel_s)[3],
                                            float (*logits_s)[32],
                                            float qS, float w0, float w1,
                                            float w2, float bb, int t) {
  float rp[NK];
  bool writer = ((t & 31) == 31);
  int h = t >> 5;
#pragma unroll
  for (int j = 0; j < NK; j++) {
    int jj = __builtin_amdgcn_readfirstlane(idx_s[j]);
    const float* kr = qkvb + (size_t)jj * QKVW + 256;
    float kv = kr[t];
    float x = fmaf(rel_s[j][0], w0,
              fmaf(rel_s[j][1], w1, fmaf(rel_s[j][2], w2, bb)));
    float r = gelu_fast(x);
    rp[j] = r;
    float u = head32_reduce(fmaf(qS, kv, r));
    if (writer) logits_s[h][j] = u;
  }
  __builtin_amdgcn_wave_barrier();
  asm volatile("s_waitcnt lgkmcnt(0)" ::: "memory");
  float mx = -3.4e38f;
#pragma unroll
  for (int j = 0; j < NK; j++) mx = fmaxf(mx, logits_s[h][j]);
  float num = 0.f, den = 0.f;
#pragma unroll
  for (int j = 0; j < NK; j++) {
    float e = __expf(logits_s[h][j] - mx);
    int jj = __builtin_amdgcn_readfirstlane(idx_s[j]);
    const float* vr = qkvb + (size_t)jj * QKVW + 512;
    float v = vr[t];
    num = fmaf(e, v + rp[j], num);
    den += e;
  }
  return num * __builtin_amdgcn_rcpf(den);
}

__global__ __launch_bounds__(256) void attn_kernel(
    const float* __restrict__ qkv, const float* __restrict__ pos,
    const int* __restrict__ knn,
    const float* __restrict__ Wp0, const float* __restrict__ bp0,
    const float* __restrict__ Wp1, const float* __restrict__ bp1,
    ushort_t* __restrict__ xcat) {
  const float SCALE = 0.17677669529663687f;  // 32^-0.5
  int bn = blockIdx.x;
  int b = bn >> 11, n = bn & (NPT - 1);
  int t = threadIdx.x;
  int g = t >> 7, c = t & 127;
  __shared__ int idx_s[32];
  __shared__ float rel_s[32][3];
  __shared__ float logits_s[8][32];
  const float* qkvb = qkv + (size_t)b * NPT * QKVW;
  if (t < 32) {
    int j = knn[(size_t)bn * 32 + t];
    idx_s[t] = j;
    const float* pn = pos + ((size_t)b * NPT + n) * 3;
    const float* pj = pos + ((size_t)b * NPT + j) * 3;
    rel_s[t][0] = pn[0] - pj[0];
    rel_s[t][1] = pn[1] - pj[1];
    rel_s[t][2] = pn[2] - pj[2];
  }
  float q = qkvb[(size_t)n * QKVW + t];
  const float* Wp = g ? Wp1 : Wp0;
  const float* bp = g ? bp1 : bp0;
  float w0 = Wp[c], w1 = Wp[128 + c], w2 = Wp[256 + c], bb = bp[c];
  float qS = q * SCALE;
  __syncthreads();
  float o = (g == 0)
      ? attn_group<16>(qkvb, idx_s, rel_s, logits_s, qS, w0, w1, w2, bb, t)
      : attn_group<32>(qkvb, idx_s, rel_s, logits_s, qS, w0, w1, w2, bb, t);
  xcat[((size_t)b * NPT + n) * DIM_ + t] = f2bf(o);
}

// ---------------------------------------------------------------------------
// Column partial sums of feats_proj. grid (B,32), 64 rows each.
// ---------------------------------------------------------------------------
__global__ __launch_bounds__(256) void colsum_kernel(const float* __restrict__ fp,
                                                     float* __restrict__ part) {
  int b = blockIdx.x, ch = blockIdx.y, t = threadIdx.x;
  const float* base = fp + ((size_t)(b * NPT + ch * 64)) * DIM_ + t;
  float s = 0.f;
  for (int r = 0; r < 64; r++) s += base[(size_t)r * DIM_];
  part[((size_t)b * 32 + ch) * DIM_ + t] = s;
}

// ---------------------------------------------------------------------------
// MSF MLP + gate fold: S=mean -> Z=gelu(S@Wfc1+b) -> av=softmax pair ->
// avWheadT[b][n][k] = bf16( WheadT[n][k] * av[b][k] )  (feeds gemm2's B).
// One block per batch, 256 threads (t = channel k).
// ---------------------------------------------------------------------------
__global__ __launch_bounds__(256) void msf_small_kernel(
    const float* __restrict__ part, const float* __restrict__ Wfc1,
    const float* __restrict__ bfc1, const float* __restrict__ Wfc2,
    const float* __restrict__ bfc2, const ushort_t* __restrict__ WheadT,
    ushort_t* __restrict__ avWheadT) {
  int b = blockIdx.x, t = threadIdx.x;
  __shared__ float S[256], Z[128], A[256];
  float s = 0.f;
  for (int ch = 0; ch < 32; ch++) s += part[((size_t)b * 32 + ch) * DIM_ + t];
  S[t] = s * (1.0f / 2048.0f);
  __syncthreads();
  if (t < 128) {
    float z = bfc1[t];
    for (int i = 0; i < 256; i++) z += S[i] * Wfc1[i * 128 + t];
    Z[t] = gelu_f(z);
  }
  __syncthreads();
  float a = bfc2[t];
  for (int j = 0; j < 128; j++) a += Z[j] * Wfc2[j * 256 + t];
  A[t] = a;
  __syncthreads();
  float pA = A[t ^ 128];
  float m = fmaxf(a, pA);
  float e = expf(a - m);
  float av = e / (e + expf(pA - m));
  ushort_t* ot = avWheadT + (size_t)b * 65536;
  for (int n = 0; n < 256; n++)
    ot[n * 256 + t] = f2bf(bf2f(WheadT[n * 256 + t]) * av);
}

// ---------------------------------------------------------------------------
extern "C" void kernel_launch(void* const* d_in, const int* in_sizes, int n_in,
                              void* d_out, int out_size, void* d_ws, size_t ws_size,
                              hipStream_t stream) {
  const float* x     = (const float*)d_in[0];
  const float* pos   = (const float*)d_in[1];
  const float* Wqkv  = (const float*)d_in[2];
  const float* Wp0   = (const float*)d_in[3];
  const float* bp0   = (const float*)d_in[4];
  const float* Wp1   = (const float*)d_in[5];
  const float* bp1   = (const float*)d_in[6];
  const float* Wproj = (const float*)d_in[7];
  const float* bproj = (const float*)d_in[8];
  const float* Wfc1  = (const float*)d_in[9];
  const float* bfc1  = (const float*)d_in[10];
  const float* Wfc2  = (const float*)d_in[11];
  const float* bfc2  = (const float*)d_in[12];
  const float* Whead = (const float*)d_in[13];
  const float* bhead = (const float*)d_in[14];
  float* out = (float*)d_out;

  // Workspace layout (~31.7 MB):
  char* ws = (char*)d_ws;
  size_t off = 0;
  int* idx = (int*)(ws + off);            off += (size_t)B_ * NPT * 32 * 4;     // 1.0 MB
  float* qkv = (float*)(ws + off);        off += (size_t)B_ * NPT * QKVW * 4;   // 25.2 MB
  float* fp = qkv;  // feats_proj reuses qkv region (qkv dead after attn)
  ushort_t* xbf = (ushort_t*)(ws + off);  off += (size_t)B_ * NPT * DIM_ * 2;   // 4.2 MB
  ushort_t* xcat = xbf;  // xbf dead after gemm0; attn writes xcat here
  ushort_t* WqkvT = (ushort_t*)(ws + off);  off += (size_t)QLEN * 2;            // 0.39 MB
  ushort_t* WprojT = (ushort_t*)(ws + off); off += (size_t)PLEN * 2;            // 0.13 MB
  ushort_t* WheadT = (ushort_t*)(ws + off); off += (size_t)PLEN * 2;            // 0.13 MB
  ushort_t* avWheadT = (ushort_t*)(ws + off); off += (size_t)B_ * PLEN * 2;     // 0.52 MB
  float* part = (float*)(ws + off);       off += (size_t)B_ * 32 * DIM_ * 4;    // 0.13 MB

  const int M = B_ * NPT;  // 8192

  convert_kernel<<<(XLEN + QLEN + 2 * PLEN) / 256, 256, 0, stream>>>(
      x, Wqkv, Wproj, Whead, xbf, WqkvT, WprojT, WheadT);
  knn_kernel<<<M / 4, 256, 0, stream>>>(pos, idx);
  gemm_mfma<0><<<dim3(QKVW / 128, M / 128), 256, 0, stream>>>(
      xbf, WqkvT, nullptr, nullptr, qkv, QKVW);
  attn_kernel<<<M, 256, 0, stream>>>(qkv, pos, idx, Wp0, bp0, Wp1, bp1, xcat);
  gemm_mfma<1><<<dim3(DIM_ / 128, M / 128), 256, 0, stream>>>(
      xcat, WprojT, bproj, nullptr, fp, DIM_);
  colsum_kernel<<<dim3(B_, 32), 256, 0, stream>>>(fp, part);
  msf_small_kernel<<<B_, 256, 0, stream>>>(part, Wfc1, bfc1, Wfc2, bfc2,
                                           WheadT, avWheadT);
  gemm_mfma<2><<<dim3(DIM_ / 128, M / 128), 256, 0, stream>>>(
      xcat, avWheadT, bhead, fp, out, DIM_);
}